// Round 1
// baseline (827.088 us; speedup 1.0000x reference)
//
#include <hip/hip_runtime.h>

// SelfAttention2D: b=8, c=512, h=w=32 (hw=1024), groups=32, heads=8, d=64
// Pipeline: gn_stats -> gn_apply -> qkv GEMM -> flash attention -> proj GEMM + residual
// Round 1: pure fp32 correctness baseline (no MFMA yet).

constexpr int Bn = 8, Cn = 512, HWn = 1024, CGn = 16, Dn = 64, C3 = 1536;

// ---------------- GroupNorm stats: one block per (b, group) ----------------
__global__ __launch_bounds__(256) void gn_stats_k(const float* __restrict__ x,
                                                  float* __restrict__ stats) {
  int bg = blockIdx.x;  // b*32 + g, 256 total
  const float4* p = (const float4*)(x + (size_t)bg * (CGn * HWn));
  float s = 0.f, ss = 0.f;
  for (int i = threadIdx.x; i < CGn * HWn / 4; i += 256) {
    float4 v = p[i];
    s += v.x + v.y + v.z + v.w;
    ss += v.x * v.x + v.y * v.y + v.z * v.z + v.w * v.w;
  }
#pragma unroll
  for (int off = 32; off; off >>= 1) {
    s += __shfl_xor(s, off);
    ss += __shfl_xor(ss, off);
  }
  __shared__ float rs[4], rss[4];
  int lane = threadIdx.x & 63, w = threadIdx.x >> 6;
  if (lane == 0) { rs[w] = s; rss[w] = ss; }
  __syncthreads();
  if (threadIdx.x == 0) {
    float S = rs[0] + rs[1] + rs[2] + rs[3];
    float SS = rss[0] + rss[1] + rss[2] + rss[3];
    const float invn = 1.0f / (CGn * HWn);
    float mu = S * invn;
    float var = SS * invn - mu * mu;
    stats[bg] = mu;
    stats[256 + bg] = rsqrtf(var + 1e-5f);
  }
}

// ---------------- GroupNorm apply (elementwise, float4) ----------------
__global__ __launch_bounds__(256) void gn_apply_k(const float* __restrict__ x,
                                                  const float* __restrict__ stats,
                                                  const float* __restrict__ gw,
                                                  const float* __restrict__ gb,
                                                  float* __restrict__ xn) {
  int i = blockIdx.x * 256 + threadIdx.x;  // float4 index, 1048576 total
  int e = i << 2;
  int ch = (e >> 10) & (Cn - 1);
  int bg = e >> 14;  // = b*32 + ch/16
  float mu = stats[bg], rstd = stats[256 + bg];
  float ga = gw[ch] * rstd;
  float be = gb[ch] - mu * ga;
  float4 v = ((const float4*)x)[i];
  v.x = fmaf(v.x, ga, be);
  v.y = fmaf(v.y, ga, be);
  v.z = fmaf(v.z, ga, be);
  v.w = fmaf(v.w, ga, be);
  ((float4*)xn)[i] = v;
}

// ---------------- fp32 GEMM: out[b] = W(MxK) @ X[b](KxN) + bias (+resid) ----------------
// K=512, N=1024 fixed. 128x128 block tile, BK=16, 256 threads, 8x8 per thread.
template <bool RESID>
__global__ __launch_bounds__(256, 2) void gemm_k(const float* __restrict__ W,
                                                 const float* __restrict__ X,
                                                 const float* __restrict__ bias,
                                                 const float* __restrict__ resid,
                                                 float* __restrict__ out, int M) {
  constexpr int Kd = 512, Nd = 1024;
  const int bn = blockIdx.x, bm = blockIdx.y, bz = blockIdx.z;
  const float* Xb = X + (size_t)bz * Kd * Nd;
  float* outb = out + (size_t)bz * M * Nd;
  __shared__ float As[16][132];  // [k][m], padded
  __shared__ float Bs[16][132];  // [k][n], padded
  const int t = threadIdx.x;
  const int tx = t & 15, ty = t >> 4;
  const int m0 = bm * 128, n0 = bn * 128;
  float acc[8][8] = {};
  for (int k0 = 0; k0 < Kd; k0 += 16) {
#pragma unroll
    for (int i = 0; i < 2; i++) {  // A tile: 128x16 -> transposed into As
      int f4 = i * 256 + t;
      int r = f4 >> 2, c = (f4 & 3) * 4;
      float4 a = *(const float4*)&W[(size_t)(m0 + r) * Kd + k0 + c];
      As[c + 0][r] = a.x;
      As[c + 1][r] = a.y;
      As[c + 2][r] = a.z;
      As[c + 3][r] = a.w;
    }
#pragma unroll
    for (int i = 0; i < 2; i++) {  // B tile: 16x128
      int f4 = i * 256 + t;
      int r = f4 >> 5, c = (f4 & 31) * 4;
      *(float4*)&Bs[r][c] = *(const float4*)&Xb[(size_t)(k0 + r) * Nd + n0 + c];
    }
    __syncthreads();
#pragma unroll
    for (int k = 0; k < 16; k++) {
      float4 a0 = *(const float4*)&As[k][ty * 8];
      float4 a1 = *(const float4*)&As[k][ty * 8 + 4];
      float4 b0 = *(const float4*)&Bs[k][tx * 8];
      float4 b1 = *(const float4*)&Bs[k][tx * 8 + 4];
      float av[8] = {a0.x, a0.y, a0.z, a0.w, a1.x, a1.y, a1.z, a1.w};
      float bv[8] = {b0.x, b0.y, b0.z, b0.w, b1.x, b1.y, b1.z, b1.w};
#pragma unroll
      for (int i = 0; i < 8; i++)
#pragma unroll
        for (int j = 0; j < 8; j++) acc[i][j] = fmaf(av[i], bv[j], acc[i][j]);
    }
    __syncthreads();
  }
#pragma unroll
  for (int i = 0; i < 8; i++) {
    const int m = m0 + ty * 8 + i;
    const float bvv = bias[m];
#pragma unroll
    for (int j = 0; j < 8; j++) {
      const int n = n0 + tx * 8 + j;
      float v = acc[i][j] + bvv;
      if (RESID) v += resid[(size_t)bz * M * Nd + (size_t)m * Nd + n];
      outb[(size_t)m * Nd + n] = v;
    }
  }
}

// ---------------- Flash attention, fp32 ----------------
// grid (16 qtiles, 8 heads, 8 batch), 256 threads.
// thread t: q-row ql = t>>2 (64 rows), k-chunk ck = t&3 (16 k each of 64-wide tile).
__global__ __launch_bounds__(256, 2) void attn_k(const float* __restrict__ qkv,
                                                 float* __restrict__ ao) {
  const int qt = blockIdx.x, head = blockIdx.y, b = blockIdx.z;
  const float* base = qkv + (size_t)b * C3 * HWn;
  const float* Qg = base + (size_t)(head * Dn) * HWn + qt * 64;
  const float* Kg = base + (size_t)(Cn + head * Dn) * HWn;
  const float* Vg = base + (size_t)(2 * Cn + head * Dn) * HWn;
  __shared__ float Qs[64][68];  // also reused as output staging
  __shared__ float Ks[64][68];
  __shared__ float Vs[64][68];
  const int t = threadIdx.x;
  const int ql = t >> 2, ck = t & 3;

  // stage Q tile (coalesced), then pull this thread's q-row into registers
#pragma unroll
  for (int i = 0; i < 4; i++) {
    int f4 = i * 256 + t;
    int r = f4 >> 4, c = (f4 & 15) * 4;
    *(float4*)&Qs[r][c] = *(const float4*)&Qg[(size_t)r * HWn + c];
  }
  __syncthreads();
  float q[64];
#pragma unroll
  for (int dd = 0; dd < 64; dd++) q[dd] = Qs[dd][ql] * 0.125f;  // 1/sqrt(64)

  float acc[64];
#pragma unroll
  for (int dd = 0; dd < 64; dd++) acc[dd] = 0.f;
  float m_run = -1e30f, l_run = 0.f;

#pragma unroll 1
  for (int kt = 0; kt < 16; kt++) {
    __syncthreads();  // previous tile fully consumed
#pragma unroll
    for (int i = 0; i < 4; i++) {
      int f4 = i * 256 + t;
      int r = f4 >> 4, c = (f4 & 15) * 4;
      *(float4*)&Ks[r][c] = *(const float4*)&Kg[(size_t)r * HWn + kt * 64 + c];
      *(float4*)&Vs[r][c] = *(const float4*)&Vg[(size_t)r * HWn + kt * 64 + c];
    }
    __syncthreads();

    float s[16];
#pragma unroll
    for (int j = 0; j < 16; j++) s[j] = 0.f;
#pragma unroll
    for (int dd = 0; dd < 64; dd++) {
      const float qv = q[dd];
      const float4 k0 = *(const float4*)&Ks[dd][ck * 16];
      const float4 k1 = *(const float4*)&Ks[dd][ck * 16 + 4];
      const float4 k2 = *(const float4*)&Ks[dd][ck * 16 + 8];
      const float4 k3 = *(const float4*)&Ks[dd][ck * 16 + 12];
      s[0] = fmaf(qv, k0.x, s[0]);  s[1] = fmaf(qv, k0.y, s[1]);
      s[2] = fmaf(qv, k0.z, s[2]);  s[3] = fmaf(qv, k0.w, s[3]);
      s[4] = fmaf(qv, k1.x, s[4]);  s[5] = fmaf(qv, k1.y, s[5]);
      s[6] = fmaf(qv, k1.z, s[6]);  s[7] = fmaf(qv, k1.w, s[7]);
      s[8] = fmaf(qv, k2.x, s[8]);  s[9] = fmaf(qv, k2.y, s[9]);
      s[10] = fmaf(qv, k2.z, s[10]); s[11] = fmaf(qv, k2.w, s[11]);
      s[12] = fmaf(qv, k3.x, s[12]); s[13] = fmaf(qv, k3.y, s[13]);
      s[14] = fmaf(qv, k3.z, s[14]); s[15] = fmaf(qv, k3.w, s[15]);
    }
    // online softmax over this 64-wide tile (4 lanes per q-row)
    float mt = s[0];
#pragma unroll
    for (int j = 1; j < 16; j++) mt = fmaxf(mt, s[j]);
    mt = fmaxf(mt, __shfl_xor(mt, 1));
    mt = fmaxf(mt, __shfl_xor(mt, 2));
    const float mn = fmaxf(m_run, mt);
    const float corr = __expf(m_run - mn);
    float p[16];
    float ps = 0.f;
#pragma unroll
    for (int j = 0; j < 16; j++) {
      p[j] = __expf(s[j] - mn);
      ps += p[j];
    }
    ps += __shfl_xor(ps, 1);
    ps += __shfl_xor(ps, 2);
    l_run = l_run * corr + ps;
    m_run = mn;
#pragma unroll
    for (int dd = 0; dd < 64; dd++) {
      const float4 v0 = *(const float4*)&Vs[dd][ck * 16];
      const float4 v1 = *(const float4*)&Vs[dd][ck * 16 + 4];
      const float4 v2 = *(const float4*)&Vs[dd][ck * 16 + 8];
      const float4 v3 = *(const float4*)&Vs[dd][ck * 16 + 12];
      float a = acc[dd] * corr;
      a = fmaf(p[0], v0.x, a);  a = fmaf(p[1], v0.y, a);
      a = fmaf(p[2], v0.z, a);  a = fmaf(p[3], v0.w, a);
      a = fmaf(p[4], v1.x, a);  a = fmaf(p[5], v1.y, a);
      a = fmaf(p[6], v1.z, a);  a = fmaf(p[7], v1.w, a);
      a = fmaf(p[8], v2.x, a);  a = fmaf(p[9], v2.y, a);
      a = fmaf(p[10], v2.z, a); a = fmaf(p[11], v2.w, a);
      a = fmaf(p[12], v3.x, a); a = fmaf(p[13], v3.y, a);
      a = fmaf(p[14], v3.z, a); a = fmaf(p[15], v3.w, a);
      acc[dd] = a;
    }
  }

  // combine the 4 k-chunks of each q-row (adjacent lanes)
#pragma unroll
  for (int dd = 0; dd < 64; dd++) {
    float a = acc[dd];
    a += __shfl_xor(a, 1);
    a += __shfl_xor(a, 2);
    acc[dd] = a;
  }
  const float inv = 1.0f / l_run;
  // stage to LDS (reuse Qs) for coalesced transposed write
#pragma unroll
  for (int dd = 0; dd < 64; dd++) {
    if ((dd >> 4) == ck) Qs[dd][ql] = acc[dd] * inv;
  }
  __syncthreads();
  float* aob = ao + (size_t)b * Cn * HWn + (size_t)(head * Dn) * HWn + qt * 64;
#pragma unroll
  for (int i = 0; i < 16; i++) {
    int lin = i * 256 + t;
    int r = lin >> 6, qc = lin & 63;
    aob[(size_t)r * HWn + qc] = Qs[r][qc];
  }
}

extern "C" void kernel_launch(void* const* d_in, const int* in_sizes, int n_in,
                              void* d_out, int out_size, void* d_ws, size_t ws_size,
                              hipStream_t stream) {
  const float* x = (const float*)d_in[0];
  const float* gn_w = (const float*)d_in[1];
  const float* gn_b = (const float*)d_in[2];
  const float* qkv_w = (const float*)d_in[3];
  const float* qkv_b = (const float*)d_in[4];
  const float* proj_w = (const float*)d_in[5];
  const float* proj_b = (const float*)d_in[6];
  float* out = (float*)d_out;

  float* ws = (float*)d_ws;
  float* stats = ws;                          // 512 floats
  float* xn = ws + 1024;                      // 8*512*1024
  float* qkv = xn + (size_t)Bn * Cn * HWn;    // 8*1536*1024
  float* ao = qkv + (size_t)Bn * C3 * HWn;    // 8*512*1024
  // total ws use: ~84 MB

  gn_stats_k<<<256, 256, 0, stream>>>(x, stats);
  gn_apply_k<<<4096, 256, 0, stream>>>(x, stats, gn_w, gn_b, xn);
  gemm_k<false><<<dim3(8, 12, 8), 256, 0, stream>>>(qkv_w, xn, qkv_b, nullptr, qkv, C3);
  attn_k<<<dim3(16, 8, 8), 256, 0, stream>>>(qkv, ao);
  gemm_k<true><<<dim3(8, 4, 8), 256, 0, stream>>>(proj_w, ao, proj_b, x, out, Cn);
}

// Round 2
// 122.436 us; speedup vs baseline: 6.7553x; 6.7553x over previous
//
#include <hip/hip_runtime.h>

// SelfAttention2D: b=8, c=512, hw=1024, groups=32, heads=8, d=64
// R2: bf16 MFMA everywhere. Pipeline:
//   gn_stats (fp32) -> wconv (W->bf16) -> gn_apply+transpose (bf16 xnT[hw][c])
//   -> qkv GEMM (writes Q,K hw-major; V c-major) -> MFMA flash attn (aoT[hw][c])
//   -> proj GEMM + bias + residual (fp32 out)

typedef __attribute__((ext_vector_type(8))) short short8v;
typedef __attribute__((ext_vector_type(4))) short short4v;
typedef __attribute__((ext_vector_type(4))) float f32x4;

constexpr int Bn = 8, Cn = 512, HWn = 1024, CGn = 16, C3 = 1536;

static __device__ inline short bf16_of(float f) {
  union { float f; unsigned u; } v{f};
  unsigned r = v.u + 0x7fffu + ((v.u >> 16) & 1u);
  return (short)(r >> 16);
}

// ---------------- GroupNorm stats: one block per (b, group) ----------------
__global__ __launch_bounds__(256) void gn_stats_k(const float* __restrict__ x,
                                                  float* __restrict__ stats) {
  int bg = blockIdx.x;
  const f32x4* p = (const f32x4*)(x + (size_t)bg * (CGn * HWn));
  float s = 0.f, ss = 0.f;
  for (int i = threadIdx.x; i < CGn * HWn / 4; i += 256) {
    f32x4 v = p[i];
    s += v.x + v.y + v.z + v.w;
    ss += v.x * v.x + v.y * v.y + v.z * v.z + v.w * v.w;
  }
#pragma unroll
  for (int off = 32; off; off >>= 1) {
    s += __shfl_xor(s, off);
    ss += __shfl_xor(ss, off);
  }
  __shared__ float rs[4], rss[4];
  int lane = threadIdx.x & 63, w = threadIdx.x >> 6;
  if (lane == 0) { rs[w] = s; rss[w] = ss; }
  __syncthreads();
  if (threadIdx.x == 0) {
    float S = rs[0] + rs[1] + rs[2] + rs[3];
    float SS = rss[0] + rss[1] + rss[2] + rss[3];
    const float invn = 1.0f / (CGn * HWn);
    float mu = S * invn;
    float var = SS * invn - mu * mu;
    stats[bg] = mu;
    stats[256 + bg] = rsqrtf(var + 1e-5f);
  }
}

// ---------------- weights fp32 -> bf16 ----------------
__global__ __launch_bounds__(256) void wconv_k(const float* __restrict__ wq,
                                               const float* __restrict__ wp,
                                               short* __restrict__ oq,
                                               short* __restrict__ op) {
  int i = blockIdx.x * 256 + threadIdx.x;  // float4 index, 262144 total
  const float* src = wq;
  short* dst = oq;
  int idx = i;
  if (i >= 196608) { src = wp; dst = op; idx = i - 196608; }
  f32x4 v = ((const f32x4*)src)[idx];
  short4v o;
  o.x = bf16_of(v.x); o.y = bf16_of(v.y); o.z = bf16_of(v.z); o.w = bf16_of(v.w);
  *(short4v*)&dst[idx * 4] = o;
}

// ---------------- GN apply + transpose -> xnT[b][hw][c] bf16 ----------------
__global__ __launch_bounds__(256) void gn_apply_t_k(const float* __restrict__ x,
                                                    const float* __restrict__ stats,
                                                    const float* __restrict__ gw,
                                                    const float* __restrict__ gb,
                                                    short* __restrict__ xnT) {
  __shared__ __align__(16) short T[64][72];
  const int hw0 = blockIdx.x * 64, c0 = blockIdx.y * 64, b = blockIdx.z;
  const float* xb = x + ((size_t)b * Cn + c0) * HWn + hw0;
  const int t = threadIdx.x;
  const int cr = t >> 4, h4 = (t & 15) * 4;
#pragma unroll
  for (int i = 0; i < 4; i++) {
    int c = cr + 16 * i;
    int cg = c0 + c;
    int bg = b * 32 + (cg >> 4);
    float mu = stats[bg], rstd = stats[256 + bg];
    float ga = gw[cg] * rstd;
    float be = gb[cg] - mu * ga;
    f32x4 v = *(const f32x4*)&xb[(size_t)c * HWn + h4];
    T[h4 + 0][c] = bf16_of(fmaf(v.x, ga, be));
    T[h4 + 1][c] = bf16_of(fmaf(v.y, ga, be));
    T[h4 + 2][c] = bf16_of(fmaf(v.z, ga, be));
    T[h4 + 3][c] = bf16_of(fmaf(v.w, ga, be));
  }
  __syncthreads();
  short* dst = xnT + ((size_t)b * HWn + hw0) * Cn + c0;
  const int hr = t >> 3, c8 = (t & 7) * 8;
#pragma unroll
  for (int i = 0; i < 2; i++) {
    int r = hr + 32 * i;
    *(short8v*)&dst[(size_t)r * Cn + c8] = *(const short8v*)&T[r][c8];
  }
}

// ---------------- bf16 MFMA GEMM: 128x128 tile, BK=32 ----------------
// A: (M,512) bf16 row-major. Bt: per-b (1024,512) bf16 row-major (= B^T).
// MODE 0: qkv epilogue (Q,K -> hw-major bf16; V -> c-major bf16), +bias.
// MODE 1: proj epilogue (fp32 out = acc + bias + resid).
__device__ inline short8v fragG(const short* buf, int row, int gk) {
  return *(const short8v*)&buf[row * 32 + ((gk ^ ((row >> 1) & 3)) << 3)];
}

template <int MODE>
__global__ __launch_bounds__(256, 2) void gemm_bf16_k(
    const short* __restrict__ A, const short* __restrict__ Bt,
    const float* __restrict__ bias, const float* __restrict__ resid,
    float* __restrict__ outF, short* __restrict__ oQ, short* __restrict__ oK,
    short* __restrict__ oV) {
  const int bn = blockIdx.x, bm = blockIdx.y, b = blockIdx.z;
  const short* Bb = Bt + (size_t)b * HWn * Cn;
  __shared__ __align__(16) short As[128 * 32];
  __shared__ __align__(16) short Bs[128 * 32];
  const int t = threadIdx.x, l = t & 63, w = t >> 6;
  const int wr = w >> 1, wc = w & 1;
  const int m0 = bm * 128, n0 = bn * 128;
  const f32x4 vzero = {0.f, 0.f, 0.f, 0.f};
  f32x4 acc[4][4];
#pragma unroll
  for (int i = 0; i < 4; i++)
#pragma unroll
    for (int j = 0; j < 4; j++) acc[i][j] = vzero;

  for (int k0 = 0; k0 < 512; k0 += 32) {
#pragma unroll
    for (int it = 0; it < 2; it++) {
      int r = (t >> 2) + 64 * it, g = t & 3, gs = g ^ ((r >> 1) & 3);
      *(short8v*)&As[r * 32 + g * 8] =
          *(const short8v*)&A[(size_t)(m0 + r) * 512 + k0 + gs * 8];
      *(short8v*)&Bs[r * 32 + g * 8] =
          *(const short8v*)&Bb[(size_t)(n0 + r) * 512 + k0 + gs * 8];
    }
    __syncthreads();
    short8v af[4], bf[4];
#pragma unroll
    for (int i = 0; i < 4; i++) af[i] = fragG(As, wr * 64 + i * 16 + (l & 15), l >> 4);
#pragma unroll
    for (int j = 0; j < 4; j++) bf[j] = fragG(Bs, wc * 64 + j * 16 + (l & 15), l >> 4);
#pragma unroll
    for (int i = 0; i < 4; i++)
#pragma unroll
      for (int j = 0; j < 4; j++)
        acc[i][j] = __builtin_amdgcn_mfma_f32_16x16x32_bf16(af[i], bf[j], acc[i][j], 0, 0, 0);
    __syncthreads();
  }

  if (MODE == 1) {
    float* outb = outF + (size_t)b * Cn * HWn;
    const float* rb = resid + (size_t)b * Cn * HWn;
#pragma unroll
    for (int i = 0; i < 4; i++)
#pragma unroll
      for (int r = 0; r < 4; r++) {
        int m = m0 + wr * 64 + i * 16 + (l >> 4) * 4 + r;
        float bv = bias[m];
#pragma unroll
        for (int j = 0; j < 4; j++) {
          int n = n0 + wc * 64 + j * 16 + (l & 15);
          size_t idx = (size_t)m * HWn + n;
          outb[idx] = acc[i][j][r] + bv + rb[idx];
        }
      }
  } else {
#pragma unroll
    for (int i = 0; i < 4; i++)
#pragma unroll
      for (int r = 0; r < 4; r++) {
        int m = m0 + wr * 64 + i * 16 + (l >> 4) * 4 + r;
        float bv = bias[m];
#pragma unroll
        for (int j = 0; j < 4; j++) {
          int n = n0 + wc * 64 + j * 16 + (l & 15);
          short h = bf16_of(acc[i][j][r] + bv);
          if (m < 512) oQ[((size_t)b * HWn + n) * 512 + m] = h;
          else if (m < 1024) oK[((size_t)b * HWn + n) * 512 + (m - 512)] = h;
          else oV[((size_t)b * 512 + (m - 1024)) * HWn + n] = h;
        }
      }
  }
}

// ---------------- MFMA flash attention ----------------
// grid (16 qtile, 8 head, 8 b), 256 threads = 4 waves; wave w owns q-rows [16w,16w+16).
// Q,K from hw-major buffers (row=hw, 512 cols); V from c-major (row=c, 1024 cols).
// S^T = mfma(K_frag, Q_frag): lane holds S[q=l&15][kk=16f+4g+r]. P via padded LDS.
__device__ inline void stage64(short* dst, const short* src, int stride, int t) {
#pragma unroll
  for (int it = 0; it < 2; it++) {
    int r = (t >> 3) + 32 * it, g = t & 7, gs = g ^ (r & 7);
    *(short8v*)&dst[r * 64 + g * 8] = *(const short8v*)&src[(size_t)r * stride + gs * 8];
  }
}
__device__ inline short8v frag64(const short* buf, int row, int gk) {
  return *(const short8v*)&buf[row * 64 + ((gk ^ (row & 7)) << 3)];
}

__global__ __launch_bounds__(256, 2) void attn_k(const short* __restrict__ qT,
                                                 const short* __restrict__ kT,
                                                 const short* __restrict__ vB,
                                                 short* __restrict__ aoT) {
  const int qt = blockIdx.x, head = blockIdx.y, b = blockIdx.z;
  __shared__ __align__(16) short Qs[64 * 64];
  __shared__ __align__(16) short Ks[64 * 64];
  __shared__ __align__(16) short Vs[64 * 64];
  __shared__ __align__(16) short Ps[4][16 * 72];
  __shared__ __align__(16) short Os[64 * 72];
  const int t = threadIdx.x, l = t & 63, w = t >> 6;
  short* Psw = &Ps[w][0];
  const f32x4 vzero = {0.f, 0.f, 0.f, 0.f};

  const short* qsrc = qT + ((size_t)b * HWn + qt * 64) * 512 + head * 64;
  const short* ksrc0 = kT + (size_t)b * HWn * 512 + head * 64;
  const short* vsrc0 = vB + ((size_t)b * 512 + head * 64) * HWn;

  stage64(Qs, qsrc, 512, t);
  __syncthreads();
  const short8v qf0 = frag64(Qs, 16 * w + (l & 15), l >> 4);
  const short8v qf1 = frag64(Qs, 16 * w + (l & 15), (l >> 4) + 4);

  f32x4 oa[4];
#pragma unroll
  for (int f = 0; f < 4; f++) oa[f] = vzero;
  float m_run = -1e30f, l_run = 0.f;

#pragma unroll 1
  for (int kt = 0; kt < 16; kt++) {
    __syncthreads();
    stage64(Ks, ksrc0 + (size_t)(kt * 64) * 512, 512, t);
    stage64(Vs, vsrc0 + kt * 64, HWn, t);
    __syncthreads();

    // QK^T (transposed form)
    f32x4 sa[4];
#pragma unroll
    for (int f = 0; f < 4; f++) {
      short8v ka0 = frag64(Ks, 16 * f + (l & 15), l >> 4);
      short8v ka1 = frag64(Ks, 16 * f + (l & 15), (l >> 4) + 4);
      sa[f] = __builtin_amdgcn_mfma_f32_16x16x32_bf16(ka0, qf0, vzero, 0, 0, 0);
      sa[f] = __builtin_amdgcn_mfma_f32_16x16x32_bf16(ka1, qf1, sa[f], 0, 0, 0);
    }

    // online softmax; lane's column q = l&15, rows kk = 16f + 4*(l>>4) + r
    float p[4][4];
    float mt = -1e30f;
#pragma unroll
    for (int f = 0; f < 4; f++)
#pragma unroll
      for (int r = 0; r < 4; r++) {
        float s = sa[f][r] * 0.125f;
        p[f][r] = s;
        mt = fmaxf(mt, s);
      }
    mt = fmaxf(mt, __shfl_xor(mt, 16));
    mt = fmaxf(mt, __shfl_xor(mt, 32));
    const float mn = fmaxf(m_run, mt);
    const float corr = __expf(m_run - mn);
    float ps = 0.f;
#pragma unroll
    for (int f = 0; f < 4; f++)
#pragma unroll
      for (int r = 0; r < 4; r++) {
        float e = __expf(p[f][r] - mn);
        p[f][r] = e;
        ps += e;
      }
    ps += __shfl_xor(ps, 16);
    ps += __shfl_xor(ps, 32);
    l_run = l_run * corr + ps;
    m_run = mn;

    // write P (bf16) to per-wave LDS: Ps[q][kk], pad 72
#pragma unroll
    for (int f = 0; f < 4; f++)
#pragma unroll
      for (int rp = 0; rp < 4; rp += 2) {
        unsigned u = (unsigned)(unsigned short)bf16_of(p[f][rp]) |
                     ((unsigned)(unsigned short)bf16_of(p[f][rp + 1]) << 16);
        *(unsigned*)&Psw[(l & 15) * 72 + 16 * f + 4 * (l >> 4) + rp] = u;
      }

    // rescale O by corr (per O-row q' = 4g+r)
#pragma unroll
    for (int r = 0; r < 4; r++) {
      float c = __shfl(corr, 4 * (l >> 4) + r);
#pragma unroll
      for (int f = 0; f < 4; f++) oa[f][r] *= c;
    }

    // PV
    short8v pa0 = *(const short8v*)&Psw[(l & 15) * 72 + (l >> 4) * 8];
    short8v pa1 = *(const short8v*)&Psw[(l & 15) * 72 + (l >> 4) * 8 + 32];
#pragma unroll
    for (int f = 0; f < 4; f++) {
      short8v vb0 = frag64(Vs, 16 * f + (l & 15), l >> 4);
      short8v vb1 = frag64(Vs, 16 * f + (l & 15), (l >> 4) + 4);
      oa[f] = __builtin_amdgcn_mfma_f32_16x16x32_bf16(pa0, vb0, oa[f], 0, 0, 0);
      oa[f] = __builtin_amdgcn_mfma_f32_16x16x32_bf16(pa1, vb1, oa[f], 0, 0, 0);
    }
  }

  // normalize + stage O to LDS, then coalesced global write
  const float inv = 1.0f / l_run;
#pragma unroll
  for (int r = 0; r < 4; r++) {
    float iv = __shfl(inv, 4 * (l >> 4) + r);
#pragma unroll
    for (int f = 0; f < 4; f++)
      Os[(16 * w + 4 * (l >> 4) + r) * 72 + 16 * f + (l & 15)] = bf16_of(oa[f][r] * iv);
  }
  __syncthreads();
  short* dst = aoT + ((size_t)b * HWn + qt * 64) * 512 + head * 64;
#pragma unroll
  for (int it = 0; it < 2; it++) {
    int r = (t >> 3) + 32 * it;
    *(short8v*)&dst[(size_t)r * 512 + (t & 7) * 8] = *(const short8v*)&Os[r * 72 + (t & 7) * 8];
  }
}

extern "C" void kernel_launch(void* const* d_in, const int* in_sizes, int n_in,
                              void* d_out, int out_size, void* d_ws, size_t ws_size,
                              hipStream_t stream) {
  const float* x = (const float*)d_in[0];
  const float* gn_w = (const float*)d_in[1];
  const float* gn_b = (const float*)d_in[2];
  const float* qkv_w = (const float*)d_in[3];
  const float* qkv_b = (const float*)d_in[4];
  const float* proj_w = (const float*)d_in[5];
  const float* proj_b = (const float*)d_in[6];
  float* out = (float*)d_out;

  char* ws = (char*)d_ws;
  float* stats = (float*)ws;                       // 512 f32
  short* wqb = (short*)(ws + 4096);                // 1536*512
  short* wpb = (short*)(ws + 4096 + 1572864);      // 512*512
  char* p = ws + 4096 + 1572864 + 524288;
  const size_t SB = (size_t)Bn * HWn * 512 * 2;    // 8 MB
  short* xnT = (short*)p;
  short* qT = (short*)(p + SB);
  short* kT = (short*)(p + 2 * SB);
  short* vB = (short*)(p + 3 * SB);
  short* aoT = (short*)(p + 4 * SB);

  gn_stats_k<<<256, 256, 0, stream>>>(x, stats);
  wconv_k<<<1024, 256, 0, stream>>>(qkv_w, proj_w, wqb, wpb);
  gn_apply_t_k<<<dim3(16, 8, 8), 256, 0, stream>>>(x, stats, gn_w, gn_b, xnT);
  gemm_bf16_k<0><<<dim3(8, 12, 8), 256, 0, stream>>>(wqb, xnT, qkv_b, nullptr,
                                                     nullptr, qT, kT, vB);
  attn_k<<<dim3(16, 8, 8), 256, 0, stream>>>(qT, kT, vB, aoT);
  gemm_bf16_k<1><<<dim3(8, 4, 8), 256, 0, stream>>>(wpb, aoT, proj_b, x,
                                                    out, nullptr, nullptr, nullptr);
}

// Round 3
// 95.545 us; speedup vs baseline: 8.6566x; 1.2815x over previous
//
#include <hip/hip_runtime.h>

// SelfAttention2D: b=8, c=512, hw=1024, groups=32, heads=8, d=64
// R3: global_load_lds staging everywhere; attn exp2+defer-max softmax, 33KB LDS
// (4 blocks/CU); qkv epilogue via packed 8B stores (V uses swapped-operand MFMA);
// XCD-chunked block swizzle on gemm/attn.

typedef __attribute__((ext_vector_type(8))) short short8v;
typedef __attribute__((ext_vector_type(4))) short short4v;
typedef __attribute__((ext_vector_type(4))) float f32x4;
typedef __attribute__((ext_vector_type(2))) unsigned uint2v;

constexpr int Bn = 8, Cn = 512, HWn = 1024, CGn = 16;

#if __has_builtin(__builtin_amdgcn_exp2f)
#define EXP2F(x) __builtin_amdgcn_exp2f(x)
#else
#define EXP2F(x) __exp2f(x)
#endif

static __device__ __forceinline__ short bf16_of(float f) {
  union { float f; unsigned u; } v{f};
  unsigned r = v.u + 0x7fffu + ((v.u >> 16) & 1u);
  return (short)(r >> 16);
}
static __device__ __forceinline__ unsigned bf16pk(float a, float b) {
  return (unsigned)(unsigned short)bf16_of(a) |
         ((unsigned)(unsigned short)bf16_of(b) << 16);
}

// async global->LDS, 16B per lane; lptr must be wave-uniform (lane i lands at
// lptr + i*16B). Global src address is per-lane.
static __device__ __forceinline__ void gload16(const void* g, void* l) {
  __builtin_amdgcn_global_load_lds(
      (const __attribute__((address_space(1))) unsigned*)g,
      (__attribute__((address_space(3))) unsigned*)l, 16, 0, 0);
}

// ---------------- GroupNorm stats: one block per (b, group) ----------------
__global__ __launch_bounds__(256) void gn_stats_k(const float* __restrict__ x,
                                                  float* __restrict__ stats) {
  int bg = blockIdx.x;
  const f32x4* p = (const f32x4*)(x + (size_t)bg * (CGn * HWn));
  float s = 0.f, ss = 0.f;
  for (int i = threadIdx.x; i < CGn * HWn / 4; i += 256) {
    f32x4 v = p[i];
    s += v.x + v.y + v.z + v.w;
    ss += v.x * v.x + v.y * v.y + v.z * v.z + v.w * v.w;
  }
#pragma unroll
  for (int off = 32; off; off >>= 1) {
    s += __shfl_xor(s, off);
    ss += __shfl_xor(ss, off);
  }
  __shared__ float rs[4], rss[4];
  int lane = threadIdx.x & 63, w = threadIdx.x >> 6;
  if (lane == 0) { rs[w] = s; rss[w] = ss; }
  __syncthreads();
  if (threadIdx.x == 0) {
    float S = rs[0] + rs[1] + rs[2] + rs[3];
    float SS = rss[0] + rss[1] + rss[2] + rss[3];
    const float invn = 1.0f / (CGn * HWn);
    float mu = S * invn;
    float var = SS * invn - mu * mu;
    stats[bg] = mu;
    stats[256 + bg] = rsqrtf(var + 1e-5f);
  }
}

// ---------------- weights fp32 -> bf16 ----------------
__global__ __launch_bounds__(256) void wconv_k(const float* __restrict__ wq,
                                               const float* __restrict__ wp,
                                               short* __restrict__ oq,
                                               short* __restrict__ op) {
  int i = blockIdx.x * 256 + threadIdx.x;  // float4 index, 262144 total
  const float* src = wq;
  short* dst = oq;
  int idx = i;
  if (i >= 196608) { src = wp; dst = op; idx = i - 196608; }
  f32x4 v = ((const f32x4*)src)[idx];
  short4v o;
  o.x = bf16_of(v.x); o.y = bf16_of(v.y); o.z = bf16_of(v.z); o.w = bf16_of(v.w);
  *(short4v*)&dst[idx * 4] = o;
}

// ---------------- GN apply + transpose -> xnT[b][hw][c] bf16 ----------------
__global__ __launch_bounds__(256) void gn_apply_t_k(const float* __restrict__ x,
                                                    const float* __restrict__ stats,
                                                    const float* __restrict__ gw,
                                                    const float* __restrict__ gb,
                                                    short* __restrict__ xnT) {
  __shared__ __align__(16) short T[64][72];
  const int hw0 = blockIdx.x * 64, c0 = blockIdx.y * 64, b = blockIdx.z;
  const float* xb = x + ((size_t)b * Cn + c0) * HWn + hw0;
  const int t = threadIdx.x;
  const int cr = t >> 4, h4 = (t & 15) * 4;
#pragma unroll
  for (int i = 0; i < 4; i++) {
    int c = cr + 16 * i;
    int cg = c0 + c;
    int bg = b * 32 + (cg >> 4);
    float mu = stats[bg], rstd = stats[256 + bg];
    float ga = gw[cg] * rstd;
    float be = gb[cg] - mu * ga;
    f32x4 v = *(const f32x4*)&xb[(size_t)c * HWn + h4];
    T[h4 + 0][c] = bf16_of(fmaf(v.x, ga, be));
    T[h4 + 1][c] = bf16_of(fmaf(v.y, ga, be));
    T[h4 + 2][c] = bf16_of(fmaf(v.z, ga, be));
    T[h4 + 3][c] = bf16_of(fmaf(v.w, ga, be));
  }
  __syncthreads();
  short* dst = xnT + ((size_t)b * HWn + hw0) * Cn + c0;
  const int hr = t >> 3, c8 = (t & 7) * 8;
#pragma unroll
  for (int i = 0; i < 2; i++) {
    int r = hr + 32 * i;
    *(short8v*)&dst[(size_t)r * Cn + c8] = *(const short8v*)&T[r][c8];
  }
}

// ---------------- bf16 MFMA GEMM: 128x128 tile, BK=32, gload_lds staging ----
// A: (M,512) row-major. Bt: per-b (1024,512) row-major (= X^T).
// MODE 0 (qkv, M=1536): Q/K blocks -> hw-major [n][m] packed 8B stores;
//   V blocks (bm>=8) use swapped-operand MFMA -> c-major [m][n] packed stores.
// MODE 1 (proj, M=512): fp32 out = acc + bias + resid, [m][n].
__device__ __forceinline__ short8v fragG(const short* buf, int row, int gk) {
  return *(const short8v*)&buf[row * 32 + ((gk ^ ((row >> 1) & 3)) << 3)];
}

template <int MODE>
__global__ __launch_bounds__(256, 2) void gemm_bf16_k(
    const short* __restrict__ A, const short* __restrict__ Bt,
    const float* __restrict__ bias, const float* __restrict__ resid,
    float* __restrict__ outF, short* __restrict__ oQ, short* __restrict__ oK,
    short* __restrict__ oV) {
  constexpr int MB = (MODE == 0) ? 12 : 4;
  constexpr int CHUNK = MB;  // blocks per XCD chunk step = 8*MB*8/8
  const int bid = blockIdx.x;
  const int swz = (bid & 7) * (8 * CHUNK) + (bid >> 3);
  const int bn = swz & 7;
  const int rest = swz >> 3;
  const int bm = rest % MB, b = rest / MB;
  const bool VBLK = (MODE == 0) && (bm >= 8);

  const short* Bb = Bt + (size_t)b * HWn * Cn;
  __shared__ __align__(16) short As[128 * 32];
  __shared__ __align__(16) short Bs[128 * 32];
  const int t = threadIdx.x, l = t & 63, w = t >> 6;
  const int wr = w >> 1, wc = w & 1;
  const int m0 = bm * 128, n0 = bn * 128;
  const f32x4 vzero = {0.f, 0.f, 0.f, 0.f};
  f32x4 acc[4][4];
#pragma unroll
  for (int i = 0; i < 4; i++)
#pragma unroll
    for (int j = 0; j < 4; j++) acc[i][j] = vzero;

  const int rA0 = w * 16 + (l >> 2);  // + it*64
  const int g0 = l & 3;

  for (int k0 = 0; k0 < 512; k0 += 32) {
#pragma unroll
    for (int it = 0; it < 2; it++) {
      int r = rA0 + it * 64;
      int gs = g0 ^ ((r >> 1) & 3);
      gload16(&A[(size_t)(m0 + r) * 512 + k0 + gs * 8], &As[it * 2048 + w * 512]);
      gload16(&Bb[(size_t)(n0 + r) * 512 + k0 + gs * 8], &Bs[it * 2048 + w * 512]);
    }
    __syncthreads();  // drains vmcnt -> LDS ready
    short8v af[4], bf[4];
#pragma unroll
    for (int i = 0; i < 4; i++) af[i] = fragG(As, wr * 64 + i * 16 + (l & 15), l >> 4);
#pragma unroll
    for (int j = 0; j < 4; j++) bf[j] = fragG(Bs, wc * 64 + j * 16 + (l & 15), l >> 4);
    if (VBLK) {
#pragma unroll
      for (int i = 0; i < 4; i++)
#pragma unroll
        for (int j = 0; j < 4; j++)
          acc[i][j] = __builtin_amdgcn_mfma_f32_16x16x32_bf16(bf[j], af[i], acc[i][j], 0, 0, 0);
    } else {
#pragma unroll
      for (int i = 0; i < 4; i++)
#pragma unroll
        for (int j = 0; j < 4; j++)
          acc[i][j] = __builtin_amdgcn_mfma_f32_16x16x32_bf16(af[i], bf[j], acc[i][j], 0, 0, 0);
    }
    __syncthreads();  // tile consumed
  }

  if (MODE == 1) {
    float* outb = outF + (size_t)b * Cn * HWn;
    const float* rb = resid + (size_t)b * Cn * HWn;
#pragma unroll
    for (int i = 0; i < 4; i++) {
      f32x4 bv = *(const f32x4*)&bias[m0 + wr * 64 + i * 16 + (l >> 4) * 4];
#pragma unroll
      for (int r = 0; r < 4; r++) {
        int m = m0 + wr * 64 + i * 16 + (l >> 4) * 4 + r;
#pragma unroll
        for (int j = 0; j < 4; j++) {
          int n = n0 + wc * 64 + j * 16 + (l & 15);
          size_t idx = (size_t)m * HWn + n;
          outb[idx] = acc[i][j][r] + bv[r] + rb[idx];
        }
      }
    }
  } else if (!VBLK) {
    // Q/K: write [n][m'] (hw-major), lane holds 4 consecutive m -> 8B stores
    short* oBase = (m0 < 512) ? oQ : oK;
    const int mc = (m0 < 512 ? m0 : m0 - 512) + wr * 64;
#pragma unroll
    for (int i = 0; i < 4; i++) {
      int mi = mc + i * 16 + (l >> 4) * 4;
      f32x4 bv = *(const f32x4*)&bias[m0 + wr * 64 + i * 16 + (l >> 4) * 4];
#pragma unroll
      for (int j = 0; j < 4; j++) {
        int n = n0 + wc * 64 + j * 16 + (l & 15);
        uint2v pk = {bf16pk(acc[i][j][0] + bv[0], acc[i][j][1] + bv[1]),
                     bf16pk(acc[i][j][2] + bv[2], acc[i][j][3] + bv[3])};
        *(uint2v*)&oBase[((size_t)b * HWn + n) * 512 + mi] = pk;
      }
    }
  } else {
    // V (swapped acc: row=n, col=m): write [m-1024][n] (c-major), 8B stores
#pragma unroll
    for (int i = 0; i < 4; i++) {
      int m = m0 + wr * 64 + i * 16 + (l & 15);
      float bv = bias[m];
      short* vrow = oV + ((size_t)b * 512 + (m - 1024)) * HWn;
#pragma unroll
      for (int j = 0; j < 4; j++) {
        int n = n0 + wc * 64 + j * 16 + (l >> 4) * 4;
        uint2v pk = {bf16pk(acc[i][j][0] + bv, acc[i][j][1] + bv),
                     bf16pk(acc[i][j][2] + bv, acc[i][j][3] + bv)};
        *(uint2v*)&vrow[n] = pk;
      }
    }
  }
}

// ---------------- MFMA flash attention ----------------
// 1024 blocks (XCD-chunked swizzle), 4 waves; wave w owns q-rows [16w,16w+16).
// gload_lds staging, exp2-domain softmax, defer-max THR=8 (log2 domain),
// O-staging aliases per-wave P slice (33KB LDS total -> 4 blocks/CU).
__device__ __forceinline__ short8v frag64(const short* buf, int row, int gk) {
  return *(const short8v*)&buf[row * 64 + ((gk ^ (row & 7)) << 3)];
}

__global__ __launch_bounds__(256, 4) void attn_k(const short* __restrict__ qT,
                                                 const short* __restrict__ kT,
                                                 const short* __restrict__ vB,
                                                 short* __restrict__ aoT) {
  const int bid = blockIdx.x;
  const int swz = (bid & 7) * 128 + (bid >> 3);
  const int qt = swz & 15, head = (swz >> 4) & 7, b = swz >> 7;
  __shared__ __align__(16) short SM[16896];  // 33792 B
  short* Ks = SM;            // 4096
  short* Vs = SM + 4096;     // 4096
  short* Ps = SM + 8192;     // 4*1152; aliased as Os[64][72] in epilogue
  short* Qs = SM + 12800;    // 4096
  const int t = threadIdx.x, l = t & 63, w = t >> 6;
  short* Psw = Ps + w * 1152;
  const f32x4 vzero = {0.f, 0.f, 0.f, 0.f};

  const short* qsrc = qT + ((size_t)b * HWn + qt * 64) * 512 + head * 64;
  const short* ksrc = kT + (size_t)b * HWn * 512 + head * 64;
  const short* vsrc = vB + ((size_t)b * 512 + head * 64) * HWn;

  const int rs0 = w * 8 + (l >> 3);  // + 32*it
  const int gg = l & 7;

#pragma unroll
  for (int it = 0; it < 2; it++) {
    int r = rs0 + 32 * it;
    int gs = gg ^ (r & 7);
    gload16(&qsrc[(size_t)r * 512 + gs * 8], &Qs[it * 2048 + w * 512]);
  }
  __syncthreads();
  const short8v qf0 = frag64(Qs, 16 * w + (l & 15), l >> 4);
  const short8v qf1 = frag64(Qs, 16 * w + (l & 15), (l >> 4) + 4);

  f32x4 oa[4];
#pragma unroll
  for (int f = 0; f < 4; f++) oa[f] = vzero;
  float m_run = -1e30f, l_run = 0.f;
  constexpr float SC = 0.1803368801111f;  // log2(e)/8

#pragma unroll 1
  for (int kt = 0; kt < 16; kt++) {
    __syncthreads();  // previous tile fully consumed
#pragma unroll
    for (int it = 0; it < 2; it++) {
      int r = rs0 + 32 * it;
      int gs = gg ^ (r & 7);
      gload16(&ksrc[(size_t)(kt * 64 + r) * 512 + gs * 8], &Ks[it * 2048 + w * 512]);
      gload16(&vsrc[(size_t)r * HWn + kt * 64 + gs * 8], &Vs[it * 2048 + w * 512]);
    }
    __syncthreads();  // vmcnt drained -> tiles ready

    // QK^T (S^T form): lane has S[q=l&15][kk=16f+4(l>>4)+r], log2-domain scale
    f32x4 sa[4];
#pragma unroll
    for (int f = 0; f < 4; f++) {
      short8v ka0 = frag64(Ks, 16 * f + (l & 15), l >> 4);
      short8v ka1 = frag64(Ks, 16 * f + (l & 15), (l >> 4) + 4);
      sa[f] = __builtin_amdgcn_mfma_f32_16x16x32_bf16(ka0, qf0, vzero, 0, 0, 0);
      sa[f] = __builtin_amdgcn_mfma_f32_16x16x32_bf16(ka1, qf1, sa[f], 0, 0, 0);
    }

    float p[4][4];
    float mt = -1e30f;
#pragma unroll
    for (int f = 0; f < 4; f++)
#pragma unroll
      for (int r = 0; r < 4; r++) {
        float s = sa[f][r] * SC;
        p[f][r] = s;
        mt = fmaxf(mt, s);
      }
    mt = fmaxf(mt, __shfl_xor(mt, 16));
    mt = fmaxf(mt, __shfl_xor(mt, 32));
    if (__any(mt > m_run + 8.f)) {  // defer-max: skip rescale when growth <= 8
      float mn = fmaxf(m_run, mt);
      float corr = EXP2F(m_run - mn);
      m_run = mn;
      l_run *= corr;
      float cr[4];
#pragma unroll
      for (int r = 0; r < 4; r++) cr[r] = __shfl(corr, 4 * (l >> 4) + r);
#pragma unroll
      for (int f = 0; f < 4; f++)
#pragma unroll
        for (int r = 0; r < 4; r++) oa[f][r] *= cr[r];
    }
    float ps = 0.f;
#pragma unroll
    for (int f = 0; f < 4; f++)
#pragma unroll
      for (int r = 0; r < 4; r++) {
        float e = EXP2F(p[f][r] - m_run);
        p[f][r] = e;
        ps += e;
      }
    ps += __shfl_xor(ps, 16);
    ps += __shfl_xor(ps, 32);
    l_run += ps;

    // P -> per-wave LDS (bf16), then PV
#pragma unroll
    for (int f = 0; f < 4; f++) {
      int o = (l & 15) * 72 + 16 * f + 4 * (l >> 4);
      *(unsigned*)&Psw[o] = bf16pk(p[f][0], p[f][1]);
      *(unsigned*)&Psw[o + 2] = bf16pk(p[f][2], p[f][3]);
    }
    short8v pa0 = *(const short8v*)&Psw[(l & 15) * 72 + (l >> 4) * 8];
    short8v pa1 = *(const short8v*)&Psw[(l & 15) * 72 + (l >> 4) * 8 + 32];
#pragma unroll
    for (int f = 0; f < 4; f++) {
      short8v vb0 = frag64(Vs, 16 * f + (l & 15), l >> 4);
      short8v vb1 = frag64(Vs, 16 * f + (l & 15), (l >> 4) + 4);
      oa[f] = __builtin_amdgcn_mfma_f32_16x16x32_bf16(pa0, vb0, oa[f], 0, 0, 0);
      oa[f] = __builtin_amdgcn_mfma_f32_16x16x32_bf16(pa1, vb1, oa[f], 0, 0, 0);
    }
  }

  // normalize; stage O into per-wave P slice; coalesced global write
  const float inv = 1.0f / l_run;
  float iv[4];
#pragma unroll
  for (int r = 0; r < 4; r++) iv[r] = __shfl(inv, 4 * (l >> 4) + r);
  short* Os = Ps;  // per-wave rows 16w.. == own P slice; in-wave LDS order ok
#pragma unroll
  for (int r = 0; r < 4; r++)
#pragma unroll
    for (int f = 0; f < 4; f++)
      Os[(16 * w + 4 * (l >> 4) + r) * 72 + 16 * f + (l & 15)] =
          bf16_of(oa[f][r] * iv[r]);
  __syncthreads();
  short* dst = aoT + ((size_t)b * HWn + qt * 64) * 512 + head * 64;
#pragma unroll
  for (int it = 0; it < 2; it++) {
    int r = (t >> 3) + 32 * it;
    *(short8v*)&dst[(size_t)r * 512 + (t & 7) * 8] =
        *(const short8v*)&Os[r * 72 + (t & 7) * 8];
  }
}

extern "C" void kernel_launch(void* const* d_in, const int* in_sizes, int n_in,
                              void* d_out, int out_size, void* d_ws, size_t ws_size,
                              hipStream_t stream) {
  const float* x = (const float*)d_in[0];
  const float* gn_w = (const float*)d_in[1];
  const float* gn_b = (const float*)d_in[2];
  const float* qkv_w = (const float*)d_in[3];
  const float* qkv_b = (const float*)d_in[4];
  const float* proj_w = (const float*)d_in[5];
  const float* proj_b = (const float*)d_in[6];
  float* out = (float*)d_out;

  char* ws = (char*)d_ws;
  float* stats = (float*)ws;                   // 512 f32
  short* wqb = (short*)(ws + 4096);            // 1536*512
  short* wpb = (short*)(ws + 4096 + 1572864);  // 512*512
  char* p = ws + 4096 + 1572864 + 524288;
  const size_t SB = (size_t)Bn * HWn * 512 * 2;  // 8 MB
  short* xnT = (short*)p;
  short* qT = (short*)(p + SB);
  short* kT = (short*)(p + 2 * SB);
  short* vB = (short*)(p + 3 * SB);
  short* aoT = (short*)(p + 4 * SB);

  gn_stats_k<<<256, 256, 0, stream>>>(x, stats);
  wconv_k<<<1024, 256, 0, stream>>>(qkv_w, proj_w, wqb, wpb);
  gn_apply_t_k<<<dim3(16, 8, 8), 256, 0, stream>>>(x, stats, gn_w, gn_b, xnT);
  gemm_bf16_k<0><<<768, 256, 0, stream>>>(wqb, xnT, qkv_b, nullptr, nullptr, qT, kT, vB);
  attn_k<<<1024, 256, 0, stream>>>(qT, kT, vB, aoT);
  gemm_bf16_k<1><<<256, 256, 0, stream>>>(wpb, aoT, proj_b, x, out, nullptr,
                                          nullptr, nullptr);
}